// Round 4
// baseline (114849.329 us; speedup 1.0000x reference)
//
#include <hip/hip_runtime.h>

#define NHID 512
#define NXW  128
#define TLEN 16384
#define STEPS (TLEN - NXW)      // 16256
#define G    64                 // persistent workgroups
#define B    512                // 8 waves per WG; 512 waves total = 1 wave per hidden row
#define POISON_U 0xAAAAAAAAu    // harness poisons d_ws with 0xAA before every launch

__device__ __forceinline__ float sigmoid_f(float v) { return 1.f / (1.f + __expf(-v)); }
__device__ __forceinline__ float tanh_f(float v)    { return 1.f - 2.f / (1.f + __expf(2.f * v)); }

// ---------------------------------------------------------------------------
// Wave-autonomous LSTM: wave (g,w) owns hidden row r = g*8+w for ALL 4 gates.
// Lane l holds U[q][r][8l..8l+8) for q=f,i,o,c (32 floats) + W[q][r][2l..2l+2)
// (8 floats). Per step: poll own 32B of h[t-1] (data-is-the-flag: published
// h+2 in (1,3) never matches 0xAA poison), 40 FMAs, xor-butterfly the 4 gate
// sums across 64 lanes (no barrier, no LDS arrays), all lanes redundantly
// compute activations + c-update (c replicated in-register), lane 0 stores
// h+2 to h_hist[t]. ZERO __syncthreads in the recurrence.
// ---------------------------------------------------------------------------
__launch_bounds__(B, 4)
__global__ void lstm_persistent(
    const float* x,
    const float* Wf, const float* Uf, const float* bf,
    const float* Wi, const float* Ui, const float* bi,
    const float* Wo, const float* Uo, const float* bo,
    const float* Wc, const float* Uc, const float* bc,
    float* h_hist)   // [STEPS][NHID] in ws (poisoned 0xAA)
{
    const int tid = threadIdx.x;
    const int g   = blockIdx.x;
    const int w   = tid >> 6;
    const int l   = tid & 63;
    const int row = g * 8 + w;

    // ---- per-lane weights (coalesced: wave covers the full 2KB U row) ----
    const float4* Uf4 = (const float4*)(Uf + (size_t)row * NHID + 8 * l);
    const float4* Ui4 = (const float4*)(Ui + (size_t)row * NHID + 8 * l);
    const float4* Uo4 = (const float4*)(Uo + (size_t)row * NHID + 8 * l);
    const float4* Uc4 = (const float4*)(Uc + (size_t)row * NHID + 8 * l);
    float4 uf0 = Uf4[0], uf1 = Uf4[1];
    float4 ui0 = Ui4[0], ui1 = Ui4[1];
    float4 uo0 = Uo4[0], uo1 = Uo4[1];
    float4 uc0 = Uc4[0], uc1 = Uc4[1];
    float2 wfv = *(const float2*)(Wf + (size_t)row * NXW + 2 * l);
    float2 wiv = *(const float2*)(Wi + (size_t)row * NXW + 2 * l);
    float2 wov = *(const float2*)(Wo + (size_t)row * NXW + 2 * l);
    float2 wcv = *(const float2*)(Wc + (size_t)row * NXW + 2 * l);
    // pin against rematerialization (R2/R3 lesson)
    #define PIN4(r) asm volatile("" : "+v"(r.x), "+v"(r.y), "+v"(r.z), "+v"(r.w));
    #define PIN2(r) asm volatile("" : "+v"(r.x), "+v"(r.y));
    PIN4(uf0) PIN4(uf1) PIN4(ui0) PIN4(ui1)
    PIN4(uo0) PIN4(uo1) PIN4(uc0) PIN4(uc1)
    PIN2(wfv) PIN2(wiv) PIN2(wov) PIN2(wcv)

    const float bsf = bf[row], bsi = bi[row], bso = bo[row], bsc = bc[row];
    float c_prev = 0.f;                  // replicated identically in all 64 lanes

    for (int t = 0; t < STEPS; ++t) {
        // x loads first: L1-resident, independent of h -> latency hides under poll
        const float x0 = x[t + 2 * l];
        const float x1 = x[t + 2 * l + 1];

        float h0, h1, h2, h3, h4, h5, h6, h7;
        if (t > 0) {
            const unsigned long long* src = (const unsigned long long*)
                (h_hist + (size_t)(t - 1) * NHID + 8 * l);
            unsigned long long v0, v1, v2, v3;
            int guard = 0;
            for (;;) {
                v0 = __hip_atomic_load(src + 0, __ATOMIC_RELAXED, __HIP_MEMORY_SCOPE_AGENT);
                v1 = __hip_atomic_load(src + 1, __ATOMIC_RELAXED, __HIP_MEMORY_SCOPE_AGENT);
                v2 = __hip_atomic_load(src + 2, __ATOMIC_RELAXED, __HIP_MEMORY_SCOPE_AGENT);
                v3 = __hip_atomic_load(src + 3, __ATOMIC_RELAXED, __HIP_MEMORY_SCOPE_AGENT);
                bool ok = ((unsigned)v0 != POISON_U) && ((unsigned)(v0 >> 32) != POISON_U)
                       && ((unsigned)v1 != POISON_U) && ((unsigned)(v1 >> 32) != POISON_U)
                       && ((unsigned)v2 != POISON_U) && ((unsigned)(v2 >> 32) != POISON_U)
                       && ((unsigned)v3 != POISON_U) && ((unsigned)(v3 >> 32) != POISON_U);
                if (ok || ++guard >= (1 << 20)) break;   // bounded: fail, don't hang
            }
            h0 = __uint_as_float((unsigned)(v0      )) - 2.f;
            h1 = __uint_as_float((unsigned)(v0 >> 32)) - 2.f;
            h2 = __uint_as_float((unsigned)(v1      )) - 2.f;
            h3 = __uint_as_float((unsigned)(v1 >> 32)) - 2.f;
            h4 = __uint_as_float((unsigned)(v2      )) - 2.f;
            h5 = __uint_as_float((unsigned)(v2 >> 32)) - 2.f;
            h6 = __uint_as_float((unsigned)(v3      )) - 2.f;
            h7 = __uint_as_float((unsigned)(v3 >> 32)) - 2.f;
        } else {
            h0 = h1 = h2 = h3 = h4 = h5 = h6 = h7 = 0.f;
        }

        // 40 FMAs: 4 gate partial sums over this lane's k-slice + x-slice
        float sf = wfv.x * x0 + wfv.y * x1;
        float si = wiv.x * x0 + wiv.y * x1;
        float so = wov.x * x0 + wov.y * x1;
        float sc = wcv.x * x0 + wcv.y * x1;
        sf += uf0.x*h0 + uf0.y*h1 + uf0.z*h2 + uf0.w*h3
            + uf1.x*h4 + uf1.y*h5 + uf1.z*h6 + uf1.w*h7;
        si += ui0.x*h0 + ui0.y*h1 + ui0.z*h2 + ui0.w*h3
            + ui1.x*h4 + ui1.y*h5 + ui1.z*h6 + ui1.w*h7;
        so += uo0.x*h0 + uo0.y*h1 + uo0.z*h2 + uo0.w*h3
            + uo1.x*h4 + uo1.y*h5 + uo1.z*h6 + uo1.w*h7;
        sc += uc0.x*h0 + uc0.y*h1 + uc0.z*h2 + uc0.w*h3
            + uc1.x*h4 + uc1.y*h5 + uc1.z*h6 + uc1.w*h7;

        // xor-butterfly: after 6 stages every lane holds the full 4 sums
        #pragma unroll
        for (int m = 1; m < 64; m <<= 1) {
            sf += __shfl_xor(sf, m, 64);
            si += __shfl_xor(si, m, 64);
            so += __shfl_xor(so, m, 64);
            sc += __shfl_xor(sc, m, 64);
        }

        // all lanes redundantly: activations (pipelined transcendentals), c, h
        const float fA = sigmoid_f(sf + bsf);
        const float iA = sigmoid_f(si + bsi);
        const float oA = sigmoid_f(so + bso);
        const float gA = tanh_f(sc + bsc);
        const float c  = fA * c_prev + iA * gA;
        c_prev = c;
        const float h = oA * tanh_f(c);

        if (l == 0)
            __hip_atomic_store(h_hist + (size_t)t * NHID + row, h + 2.f,
                               __ATOMIC_RELAXED, __HIP_MEMORY_SCOPE_AGENT);
    }
}

// ---------------------------------------------------------------------------
// epilogue: mu[t] = Ahy . (h_hist[t] - 2) + by   (one wave per t)
// ---------------------------------------------------------------------------
__global__ void mu_kernel(const float* __restrict__ h_hist,
                          const float* __restrict__ Ahy,
                          const float* __restrict__ by,
                          float* __restrict__ outp, int steps)
{
    int wave = threadIdx.x >> 6;
    int lane = threadIdx.x & 63;
    int t = blockIdx.x * 4 + wave;
    if (t >= steps) return;
    const float* h = h_hist + (size_t)t * NHID;
    float p = 0.f;
    #pragma unroll
    for (int e = 0; e < 8; e++)
        p += Ahy[e * 64 + lane] * (h[e * 64 + lane] - 2.0f);
    #pragma unroll
    for (int off = 32; off; off >>= 1) p += __shfl_down(p, off, 64);
    if (lane == 0) outp[t] = p + by[0];
}

// ---------------------------------------------------------------------------
extern "C" void kernel_launch(void* const* d_in, const int* in_sizes, int n_in,
                              void* d_out, int out_size, void* d_ws, size_t ws_size,
                              hipStream_t stream)
{
    const float* x  = (const float*)d_in[0];
    const float* Wf = (const float*)d_in[1];
    const float* Uf = (const float*)d_in[2];
    const float* bf = (const float*)d_in[3];
    const float* Wi = (const float*)d_in[4];
    const float* Ui = (const float*)d_in[5];
    const float* bi = (const float*)d_in[6];
    const float* Wo = (const float*)d_in[7];
    const float* Uo = (const float*)d_in[8];
    const float* bo = (const float*)d_in[9];
    const float* Wc = (const float*)d_in[10];
    const float* Uc = (const float*)d_in[11];
    const float* bc = (const float*)d_in[12];
    const float* Ahy = (const float*)d_in[13];
    const float* by  = (const float*)d_in[14];

    float* h_hist = (float*)d_ws;   // STEPS*NHID*4 = ~33.3 MB, poisoned 0xAA

    lstm_persistent<<<G, B, 0, stream>>>(x, Wf, Uf, bf, Wi, Ui, bi,
                                         Wo, Uo, bo, Wc, Uc, bc, h_hist);
    int muBlocks = (STEPS + 3) / 4;
    mu_kernel<<<muBlocks, 256, 0, stream>>>(h_hist, Ahy, by, (float*)d_out, STEPS);
}

// Round 6
// 25611.755 us; speedup vs baseline: 4.4842x; 4.4842x over previous
//
#include <hip/hip_runtime.h>

#define NHID 512
#define NXW  128
#define TLEN 16384
#define STEPS (TLEN - NXW)      // 16256
#define G    32                 // persistent workgroups
#define B    512                // 8 waves per WG
#define RPW  16                 // hidden rows owned per WG
#define RSLOTS 8                // sync ring depth (32 KB -> stays IC/L2-hot)

#define FOR4(M)  M(0) M(1) M(2) M(3)
#define FOR16(M) M(0) M(1) M(2) M(3) M(4) M(5) M(6) M(7) \
                 M(8) M(9) M(10) M(11) M(12) M(13) M(14) M(15)

__device__ __forceinline__ float sigmoid_f(float v) { return 1.f / (1.f + __expf(-v)); }
__device__ __forceinline__ float tanh_f(float v)    { return 1.f - 2.f / (1.f + __expf(2.f * v)); }

// ---------------------------------------------------------------------------
// R3 skeleton + hot-ring sync.
// WG g owns rows [g*16, g*16+16). 8 waves = 8 k-slices of 64.
// Lane l = output (gate q=l>>4, row g*16+(l&15)); wave w polls h-slice
// [w*64, w*64+64) of the ring.
// Ring word = {tag:32 | h_bits:32}; consumer of step t polls slot (t-1)&7
// until tag == t-1. Harness 0xAA poison = tag 0xAAAAAAAA, never a valid t,
// so stale launches can't validate. Slot reuse is race-free: observing all
// tags t-1 proves every WG completed step t-1, i.e. finished reading every
// tag <= t-2, so overwriting slot t&7 (holding tag t-8) is safe.
// h_hist gets plain (non-sync) stores purely for the mu epilogue.
// ---------------------------------------------------------------------------
__launch_bounds__(B, 2)
__global__ void lstm_persistent(
    const float* x,
    const float* Wf, const float* Uf, const float* bf,
    const float* Wi, const float* Ui, const float* bi,
    const float* Wo, const float* Uo, const float* bo,
    const float* Wc, const float* Uc, const float* bc,
    unsigned long long* ring,     // [RSLOTS][NHID] packed {tag,h}
    float* h_hist)                // [STEPS][NHID] for mu only
{
    __shared__ float x_win[256];                    // x ring: refill every 128 steps
    __shared__ __align__(16) float h_buf[8][64];    // per-wave h-slice staging
    __shared__ float partials[2][B];                // double-buffered

    const int tid = threadIdx.x;
    const int g   = blockIdx.x;
    const int w   = tid >> 6;            // wave = k-slice 0..7
    const int l   = tid & 63;            // output 0..63
    const int q   = l >> 4;              // gate 0=f 1=i 2=o 3=c
    const int row = g * RPW + (l & 15);

    const float* Utab[4] = {Uf, Ui, Uo, Uc};
    const float* Wtab[4] = {Wf, Wi, Wo, Wc};
    const float* Btab[4] = {bf, bi, bo, bc};

    // load + pin weights: 64 U floats + 16 W floats per thread (R3-proven)
    const float4* Up = (const float4*)(Utab[q] + (size_t)row * NHID + w * 64);
    #define DECLU(i) float4 u##i = Up[i];
    FOR16(DECLU)
    const float4* Wp = (const float4*)(Wtab[q] + row * NXW + w * 16);
    #define DECLW(i) float4 wv##i = Wp[i];
    FOR4(DECLW)
    #define PIN(r) asm volatile("" : "+v"(r.x), "+v"(r.y), "+v"(r.z), "+v"(r.w));
    #define PINU(i) PIN(u##i)
    FOR16(PINU)
    #define PINW(i) PIN(wv##i)
    FOR4(PINW)

    float bias = 0.f, c_prev = 0.f;
    if (w == 0) bias = Btab[q][row];

    h_buf[w][l] = 0.f;                   // h[-1] = 0 (own wave reads only)

    for (int t = 0; t < STEPS; ++t) {
        if ((t & 127) == 0) {            // x window refill (covers x[t..t+255])
            __syncthreads();
            if (tid < 256) {
                int gi = t + tid;
                x_win[tid] = (gi < TLEN) ? x[gi] : 0.f;
            }
            __syncthreads();
        }

        // x-projection partial (independent of h -> overlaps producer latency)
        float xacc = 0.f;
        {
            const int xb = (t & 127) + w * 16;
            #define XF(i) xacc += wv##i.x * x_win[xb + 4*i]     \
                                + wv##i.y * x_win[xb + 4*i + 1] \
                                + wv##i.z * x_win[xb + 4*i + 2] \
                                + wv##i.w * x_win[xb + 4*i + 3];
            FOR4(XF)
        }

        // poll own 8B ring word of h[t-1]: hot line, tag-validated
        if (t > 0) {
            const unsigned long long* src =
                ring + ((size_t)((t - 1) & (RSLOTS - 1)) << 9) + (w * 64 + l);
            const unsigned want = (unsigned)(t - 1);
            unsigned long long vv; int guard = 0;
            do {
                vv = __hip_atomic_load(src, __ATOMIC_RELAXED, __HIP_MEMORY_SCOPE_AGENT);
            } while ((unsigned)(vv >> 32) != want && ++guard < (1 << 20));
            h_buf[w][l] = __uint_as_float((unsigned)vv);
        }

        // U @ h slice: 64 FMA vs wave-uniform LDS broadcast reads
        float acc = xacc;
        const float4* hb4 = (const float4*)h_buf[w];
        #define UF(i) { float4 hv = hb4[i];                       \
                        acc += u##i.x * hv.x + u##i.y * hv.y      \
                             + u##i.z * hv.z + u##i.w * hv.w; }
        FOR16(UF)
        partials[t & 1][(w << 6) | l] = acc;
        __syncthreads();                 // the ONE per-step barrier

        // wave-0 tail: reduce 8 k-slices, activate, combine, publish to ring
        if (w == 0) {
            const float* p = partials[t & 1];
            float pre = acc + bias;
            #pragma unroll
            for (int s2 = 1; s2 < 8; ++s2) pre += p[s2 * 64 + l];
            float a = (l < 48) ? sigmoid_f(pre) : tanh_f(pre);   // f,i,o / g
            float ai = __shfl(a, l + 16, 64);
            float ao = __shfl(a, l + 32, 64);
            float ag = __shfl(a, l + 48, 64);
            if (l < 16) {
                float c = a * c_prev + ai * ag;
                c_prev = c;
                float h = ao * tanh_f(c);
                unsigned long long pv =
                    ((unsigned long long)(unsigned)t << 32)
                    | (unsigned long long)__float_as_uint(h);
                __hip_atomic_store(
                    ring + ((size_t)(t & (RSLOTS - 1)) << 9) + row, pv,
                    __ATOMIC_RELAXED, __HIP_MEMORY_SCOPE_AGENT);
                h_hist[(size_t)t * NHID + row] = h;   // mu only, off-path
            }
        }
    }
}

// ---------------------------------------------------------------------------
// epilogue: mu[t] = Ahy . h_hist[t] + by   (one wave per t)
// ---------------------------------------------------------------------------
__global__ void mu_kernel(const float* __restrict__ h_hist,
                          const float* __restrict__ Ahy,
                          const float* __restrict__ by,
                          float* __restrict__ outp, int steps)
{
    int wave = threadIdx.x >> 6;
    int lane = threadIdx.x & 63;
    int t = blockIdx.x * 4 + wave;
    if (t >= steps) return;
    const float* h = h_hist + (size_t)t * NHID;
    float p = 0.f;
    #pragma unroll
    for (int e = 0; e < 8; e++)
        p += Ahy[e * 64 + lane] * h[e * 64 + lane];
    #pragma unroll
    for (int off = 32; off; off >>= 1) p += __shfl_down(p, off, 64);
    if (lane == 0) outp[t] = p + by[0];
}

// ---------------------------------------------------------------------------
extern "C" void kernel_launch(void* const* d_in, const int* in_sizes, int n_in,
                              void* d_out, int out_size, void* d_ws, size_t ws_size,
                              hipStream_t stream)
{
    const float* x  = (const float*)d_in[0];
    const float* Wf = (const float*)d_in[1];
    const float* Uf = (const float*)d_in[2];
    const float* bf = (const float*)d_in[3];
    const float* Wi = (const float*)d_in[4];
    const float* Ui = (const float*)d_in[5];
    const float* bi = (const float*)d_in[6];
    const float* Wo = (const float*)d_in[7];
    const float* Uo = (const float*)d_in[8];
    const float* bo = (const float*)d_in[9];
    const float* Wc = (const float*)d_in[10];
    const float* Uc = (const float*)d_in[11];
    const float* bc = (const float*)d_in[12];
    const float* Ahy = (const float*)d_in[13];
    const float* by  = (const float*)d_in[14];

    unsigned long long* ring = (unsigned long long*)d_ws;        // 32 KB
    float* h_hist = (float*)((char*)d_ws + RSLOTS * NHID * 8);   // ~33.3 MB

    lstm_persistent<<<G, B, 0, stream>>>(x, Wf, Uf, bf, Wi, Ui, bi,
                                         Wo, Uo, bo, Wc, Uc, bc, ring, h_hist);
    int muBlocks = (STEPS + 3) / 4;
    mu_kernel<<<muBlocks, 256, 0, stream>>>(h_hist, Ahy, by, (float*)d_out, STEPS);
}